// Round 9
// baseline (292.925 us; speedup 1.0000x reference)
//
#include <hip/hip_runtime.h>

typedef unsigned int u32;
typedef unsigned short u16;
typedef __attribute__((ext_vector_type(8))) short bf16x8;  // 8 bf16 = 4 VGPRs
typedef __attribute__((ext_vector_type(4))) float f32x4;

#define KN 8192
#define DD 256
#define HW 1024
#define NP 32768
#define SPLITS 2
#define KSPLIT 4096
#define PXT 128
#define NTT 128

__device__ __forceinline__ u16 rne_bf16(float x) {
    u32 u = __float_as_uint(x);
    return (u16)((u + 0x7FFF + ((u >> 16) & 1)) >> 16);
}

__device__ __forceinline__ void glds16(const void* g, void* ldsbase) {
    __builtin_amdgcn_global_load_lds((const __attribute__((address_space(1))) u32*)g,
                                     (__attribute__((address_space(3))) u32*)ldsbase, 16, 0, 0);
}

// ---------------- merged prep: enorm | eT/eTf transpose | A build (R8-proven) ----------------
__global__ void prep_kernel(const float* __restrict__ e, const float* __restrict__ z,
                            u16* __restrict__ eT, float* __restrict__ eTf,
                            float* __restrict__ e2f, u16* __restrict__ A) {
    const int t = threadIdx.x;
    const int bid = blockIdx.x;
    if (bid < 32) {
        int k = bid * 256 + t;
        float acc = 0.f;
#pragma unroll 8
        for (int d = 0; d < DD; ++d) {
            float v = e[(size_t)d * KN + k];
            acc = fmaf(v, v, acc);
        }
        e2f[k] = acc;
    } else if (bid < 544) {
        __shared__ float tt[64][65];
        const int b2 = bid - 32;
        const int kt = b2 & 127;
        const int dt = b2 >> 7;
        const float* ep = e + (size_t)(dt * 64) * KN + kt * 64;
        {
            int k = t & 63, d0 = t >> 6;
#pragma unroll
            for (int j = 0; j < 16; ++j) tt[d0 + j * 4][k] = ep[(size_t)(d0 + j * 4) * KN + k];
        }
        __syncthreads();
        int k = t >> 2, c0 = (t & 3) * 16;
        u16 hi[16];
        float fv[16];
#pragma unroll
        for (int j = 0; j < 16; ++j) {
            float v = tt[c0 + j][k];
            fv[j] = v;
            hi[j] = rne_bf16(v);
        }
        u16* rowp = eT + (size_t)(kt * 64 + k) * 256 + dt * 64 + c0;
        *(uint4*)(rowp) = *(uint4*)(hi);
        *(uint4*)(rowp + 8) = *(uint4*)(hi + 8);
        float* rowpf = eTf + (size_t)(kt * 64 + k) * 256 + dt * 64 + c0;
#pragma unroll
        for (int j = 0; j < 4; ++j) *(float4*)(rowpf + j * 4) = *(float4*)(fv + j * 4);
    } else {
        __shared__ float tt[64][65];
        const int b3 = bid - 544;
        const int pt = b3 & 15;
        const int dt = (b3 >> 4) & 3;
        const int b  = b3 >> 6;
        const float* zp = z + (size_t)b * (DD * HW) + (size_t)(dt * 64) * HW + pt * 64;
        {
            int p = t & 63, d0 = t >> 6;
#pragma unroll
            for (int j = 0; j < 16; ++j) tt[d0 + j * 4][p] = zp[(size_t)(d0 + j * 4) * HW + p];
        }
        __syncthreads();
        int p = t >> 2, c0 = (t & 3) * 16;
        int n = b * HW + pt * 64 + p;
        u16 hi[16];
#pragma unroll
        for (int j = 0; j < 16; ++j) hi[j] = rne_bf16(tt[c0 + j][p]);
        u16* rowp = A + (size_t)n * 256 + dt * 64 + c0;
        *(uint4*)(rowp) = *(uint4*)(hi);
        *(uint4*)(rowp + 8) = *(uint4*)(hi + 8);
    }
}

// ---------------- main: MFMA distance GEMM + streaming argmin (R7/R8-proven, frozen) ----------------
__launch_bounds__(256, 2)
__global__ void argmin_mfma_kernel(const u16* __restrict__ A,   // [32768][256]
                                   const u16* __restrict__ eT,  // [8192][256]
                                   const float* __restrict__ e2f,
                                   int* __restrict__ keys) {    // [3][2][NP]
    __shared__ u16 Ast[4][PXT * 64];  // 64 KB resident A, XOR-swizzled slots
    __shared__ u16 Bst[NTT * 64];     // 16 KB streamed B

    const int t = threadIdx.x;
    const int w = t >> 6;
    const int l = t & 63;
    const int split = blockIdx.x & 1;
    const int pxt   = blockIdx.x >> 1;
    const int px0 = pxt * PXT;
    const int kb0 = split * KSPLIT;

    const int swz  = (l & 7) ^ ((l >> 3) & 7);
    const int srow = l >> 3;
    const int fr = l & 15;
    const int g  = l >> 4;

#pragma unroll
    for (int c = 0; c < 4; ++c)
#pragma unroll
        for (int i = 0; i < 4; ++i) {
            int r0 = w * 32 + i * 8;
            const u16* gp = A + (size_t)(px0 + r0 + srow) * 256 + c * 64 + swz * 8;
            glds16(gp, &Ast[c][r0 * 64]);
        }

    int b1[8], b2[8];
#pragma unroll
    for (int i = 0; i < 8; ++i) { b1[i] = 0x7FFFFFFF; b2[i] = 0x7FFFFFFF; }

    for (int nt = 0; nt < KSPLIT / NTT; ++nt) {
        const int n0 = kb0 + nt * NTT;
        f32x4 acc[2][8];
#pragma unroll
        for (int mi = 0; mi < 2; ++mi)
#pragma unroll
            for (int ni = 0; ni < 8; ++ni) acc[mi][ni] = (f32x4){0.f, 0.f, 0.f, 0.f};

        for (int kit = 0; kit < 4; ++kit) {
            __syncthreads();
#pragma unroll
            for (int i = 0; i < 4; ++i) {
                int r0 = w * 32 + i * 8;
                const u16* gp = eT + (size_t)(n0 + r0 + srow) * 256 + kit * 64 + swz * 8;
                glds16(gp, &Bst[r0 * 64]);
            }
            __syncthreads();
#pragma unroll
            for (int kc = 0; kc < 2; ++kc) {
                bf16x8 af[2], bfr[8];
#pragma unroll
                for (int mi = 0; mi < 2; ++mi) {
                    int row = w * 32 + mi * 16 + fr;
                    int slt = (kc * 4 + g) ^ (row & 7);
                    af[mi] = *(const bf16x8*)&Ast[kit][row * 64 + slt * 8];
                }
#pragma unroll
                for (int ni = 0; ni < 8; ++ni) {
                    int row = ni * 16 + fr;
                    int slt = (kc * 4 + g) ^ (row & 7);
                    bfr[ni] = *(const bf16x8*)&Bst[row * 64 + slt * 8];
                }
#pragma unroll
                for (int mi = 0; mi < 2; ++mi)
#pragma unroll
                    for (int ni = 0; ni < 8; ++ni)
                        acc[mi][ni] = __builtin_amdgcn_mfma_f32_16x16x32_bf16(
                            af[mi], bfr[ni], acc[mi][ni], 0, 0, 0);
            }
        }

        float e2c[8];
        int   kc8[8];
#pragma unroll
        for (int ni = 0; ni < 8; ++ni) {
            kc8[ni] = n0 + ni * 16 + fr;
            e2c[ni] = e2f[kc8[ni]] * 256.f;
        }
#pragma unroll
        for (int mi = 0; mi < 2; ++mi)
#pragma unroll
            for (int r = 0; r < 4; ++r) {
                int ky[8];
#pragma unroll
                for (int ni = 0; ni < 8; ++ni) {
                    float d = fmaf(acc[mi][ni][r], -512.f, e2c[ni]);
                    ky[ni] = (int)d * 8192 + kc8[ni];
                }
                int m0 = min(min(ky[0], ky[1]), ky[2]);
                int m1 = min(min(ky[3], ky[4]), ky[5]);
                int m2 = min(min(ky[6], ky[7]), m0);
                int kmin = min(m1, m2);
                int i8 = mi * 4 + r;
                int v1 = min(b1[i8], kmin);
                int x  = max(b1[i8], kmin);
                b2[i8] = min(b2[i8], x);
                b1[i8] = v1;
            }
    }

    {
        int* k1 = keys + split * NP;
        int* k2 = keys + (2 + split) * NP;
        int* k3 = keys + (4 + split) * NP;
#pragma unroll
        for (int i = 0; i < 8; ++i) {
            int c1 = b1[i], c2 = b2[i], c3 = 0x7FFFFFFF;
#pragma unroll
            for (int m = 1; m < 16; m <<= 1) {
                int a1 = __shfl_xor(c1, m, 64);
                int a2 = __shfl_xor(c2, m, 64);
                int a3 = __shfl_xor(c3, m, 64);
                int m1 = min(c1, a1);
                int xx = max(c1, a1);
                int mn2 = min(c2, a2);
                int m2 = min(xx, mn2);
                int m3 = min(min(max(c2, a2), max(xx, mn2)), min(c3, a3));
                c1 = m1; c2 = m2; c3 = m3;
            }
            if (fr == 0) {
                int mi = i >> 2, r = i & 3;
                int row = px0 + w * 32 + mi * 16 + g * 4 + r;
                k1[row] = c1;
                k2[row] = c2;
                k3[row] = c3;
            }
        }
    }
}

// -------- finalize (fast-ws): z read ONCE; out written from codeword rows;
//          loss = sum(dval_win + ||z||^2) -- no second z pass --------
__global__ void finalize_kernel(const int* __restrict__ keys,
                                const float* __restrict__ z,
                                const float* __restrict__ eTf,
                                const float* __restrict__ e2f,
                                float* __restrict__ out,
                                float* __restrict__ loss) {
    __shared__ float zt[DD * 65];     // 66.6 KB [d][p]
    __shared__ float qt[DD * 65];     // 66.6 KB [d][p] winning codeword rows
    __shared__ int   kc[384];
    __shared__ float dval[448];       // 384 candidate dists + 64 z^2
    __shared__ int   kidx[64];
    const int t = threadIdx.x;
    const int n0 = blockIdx.x * 64;
    const float* zp = z + (size_t)(n0 >> 10) * (DD * HW) + (n0 & (HW - 1));

    for (int i = t; i < DD * 64; i += 256) {
        int d = i >> 6, p = i & 63;
        zt[d * 65 + p] = zp[(size_t)d * HW + p];   // coalesced, z read once
    }
    for (int i = t; i < 384; i += 256)
        kc[i] = keys[(i % 6) * NP + n0 + i / 6] & 8191;
    __syncthreads();

    const int l = t & 63, w = t >> 6;
    const int j = l & 15;   // lane within 16-lane task group
    const int s = l >> 4;   // group id within wave
    for (int it = 0; it < 28; ++it) {
        int task = it * 16 + w * 4 + s;     // 0..447; branch uniform per it
        float a = 0.f;
        if (task < 384) {                   // candidate dot z.e
            int p = task / 6;
            int k = kc[task];
            const float* er = eTf + (size_t)k * 256;
#pragma unroll
            for (int cc = 0; cc < 16; ++cc)
                a = fmaf(zt[(cc * 16 + j) * 65 + p], er[cc * 16 + j], a);
            a += __shfl_xor(a, 1, 64);
            a += __shfl_xor(a, 2, 64);
            a += __shfl_xor(a, 4, 64);
            a += __shfl_xor(a, 8, 64);
            if (j == 0) dval[task] = fmaf(-2.f, a, e2f[k]);
        } else {                            // ||z_p||^2
            int p = task - 384;
#pragma unroll
            for (int cc = 0; cc < 16; ++cc) {
                float v = zt[(cc * 16 + j) * 65 + p];
                a = fmaf(v, v, a);
            }
            a += __shfl_xor(a, 1, 64);
            a += __shfl_xor(a, 2, 64);
            a += __shfl_xor(a, 4, 64);
            a += __shfl_xor(a, 8, 64);
            if (j == 0) dval[task] = a;
        }
    }
    __syncthreads();
    if (t < 64) {   // wave 0: select winner, fold loss
        float bv = dval[t * 6];
        int   bk = kc[t * 6];
#pragma unroll
        for (int c = 1; c < 6; ++c) {
            float dv = dval[t * 6 + c];
            int   kk = kc[t * 6 + c];
            if (dv < bv || (dv == bv && kk < bk)) { bv = dv; bk = kk; }
        }
        kidx[t] = bk;
        float part = bv + dval[384 + t];    // ||q-z||^2 = (e2-2qz) + z2, exact fp32
#pragma unroll
        for (int off = 32; off > 0; off >>= 1) part += __shfl_down(part, off, 64);
        if (t == 0) atomicAdd(loss, part * (1.25f / 8388608.f));
    }
    __syncthreads();

    // bounce 64 winning eTf rows into qt[d][p] (writes (t+m)%32: 2-way, free)
    for (int m = 0; m < 64; ++m)
        qt[t * 65 + m] = eTf[(size_t)kidx[m] * 256 + t];
    __syncthreads();

    // out = codeword exactly (== z + (q-z) within 1 ulp); coalesced 256B/wave
    const int p = t & 63, q = t >> 6;
    float* outp = out + (size_t)(n0 >> 10) * (DD * HW) + (n0 & (HW - 1)) + p;
#pragma unroll 8
    for (int i = 0; i < 64; ++i) {
        int d = q * 64 + i;
        outp[(size_t)d * HW] = qt[d * 65 + p];
    }
}

// -------- slow-ws path (R7-proven): separate combine + gather --------
__global__ void combine_kernel(const int* __restrict__ keys,
                               const float* __restrict__ z,
                               const float* __restrict__ eTf,
                               const float* __restrict__ e2f,
                               int* __restrict__ idx) {
    __shared__ float zt[DD * 65];
    __shared__ int   kc[384];
    __shared__ float dval[384];
    const int t = threadIdx.x;
    const int n0 = blockIdx.x * 64;
    const float* zp = z + (size_t)(n0 >> 10) * (DD * HW) + (n0 & (HW - 1));
    for (int i = t; i < DD * 64; i += 256) {
        int d = i >> 6, p = i & 63;
        zt[d * 65 + p] = zp[(size_t)d * HW + p];
    }
    for (int i = t; i < 384; i += 256)
        kc[i] = keys[(i % 6) * NP + n0 + i / 6] & 8191;
    __syncthreads();

    const int l = t & 63, w = t >> 6;
    const int j = l & 15;
    const int s = l >> 4;
#pragma unroll 2
    for (int it = 0; it < 24; ++it) {
        int dot = it * 16 + w * 4 + s;
        int p = dot / 6;
        int k = kc[dot];
        const float* er = eTf + (size_t)k * 256;
        float a = 0.f;
#pragma unroll
        for (int cc = 0; cc < 16; ++cc)
            a = fmaf(zt[(cc * 16 + j) * 65 + p], er[cc * 16 + j], a);
        a += __shfl_xor(a, 1, 64);
        a += __shfl_xor(a, 2, 64);
        a += __shfl_xor(a, 4, 64);
        a += __shfl_xor(a, 8, 64);
        if (j == 0) dval[dot] = fmaf(-2.f, a, e2f[k]);
    }
    __syncthreads();
    if (t < 64) {
        float bv = dval[t * 6];
        int   bk = kc[t * 6];
#pragma unroll
        for (int c = 1; c < 6; ++c) {
            float dv = dval[t * 6 + c];
            int   kk = kc[t * 6 + c];
            if (dv < bv || (dv == bv && kk < bk)) { bv = dv; bk = kk; }
        }
        idx[n0 + t] = bk;
    }
}

__global__ void gather_slow_kernel(const float* __restrict__ z,
                                   const float* __restrict__ e,
                                   const int* __restrict__ idx,
                                   float* __restrict__ out,
                                   float* __restrict__ loss) {
    const int t = threadIdx.x;
    const int n0 = blockIdx.x * 64;
    __shared__ int kidx[64];
    if (t < 64) kidx[t] = idx[n0 + t];
    __syncthreads();

    const int p = t & 63;
    const int d0 = t >> 6;
    const size_t base = (size_t)(n0 >> 10) * (DD * HW) + (n0 & (HW - 1)) + p;
    const int kk = kidx[p];

    float acc = 0.f;
    for (int d = d0; d < DD; d += 4) {
        float ev = e[(size_t)d * KN + kk];
        float zv = z[base + (size_t)d * HW];
        out[base + (size_t)d * HW] = zv + (ev - zv);
        float df = ev - zv;
        acc = fmaf(df, df, acc);
    }
#pragma unroll
    for (int off = 32; off > 0; off >>= 1) acc += __shfl_down(acc, off, 64);
    __shared__ float part[4];
    if ((t & 63) == 0) part[t >> 6] = acc;
    __syncthreads();
    if (t == 0) {
        float s = (part[0] + part[1] + part[2] + part[3]) * (1.25f / 8388608.f);
        atomicAdd(loss, s);
    }
}

extern "C" void kernel_launch(void* const* d_in, const int* in_sizes, int n_in,
                              void* d_out, int out_size, void* d_ws, size_t ws_size,
                              hipStream_t stream) {
    const float* z = (const float*)d_in[0];   // [32,256,32,32] fp32
    const float* e = (const float*)d_in[1];   // [256,8192] fp32
    float* out = (float*)d_out;
    float* loss = out + (size_t)NP * DD;      // element 8388608

    char* ob = (char*)d_out;
    char* ws = (char*)d_ws;
    u16* Acat = (u16*)ob;                            // [0, 16Mi) — consumed by argmin
    u16* eT   = (u16*)(ob + ((size_t)16 << 20));     // [16Mi, 20Mi) — consumed by argmin

    float* e2f = (float*)ws;                         // 32 KB (proven-safe region)
    int*   idx = (int*)(ws + (32 << 10));            // 128 KB
    int*   keys;
    float* eTf;
    const bool fastws = ws_size >= ((size_t)10 << 20);
    if (fastws) {
        keys = (int*)(ws + (160 << 10));             // 768 KB @ 160K
        eTf  = (float*)(ws + ((size_t)1 << 20));     // 8 MB @ 1M
    } else {
        keys = (int*)(ob + ((size_t)20 << 20));      // d_out scratch (R6-proven)
        eTf  = (float*)(ob + ((size_t)23 << 20));
    }

    prep_kernel<<<2592, 256, 0, stream>>>(e, z, eT, eTf, e2f, Acat);
    argmin_mfma_kernel<<<SPLITS * (NP / PXT), 256, 0, stream>>>(Acat, eT, e2f, keys);
    hipMemsetAsync(loss, 0, sizeof(float), stream);
    if (fastws) {
        finalize_kernel<<<NP / 64, 256, 0, stream>>>(keys, z, eTf, e2f, out, loss);
    } else {
        combine_kernel<<<NP / 64, 256, 0, stream>>>(keys, z, eTf, e2f, idx);
        gather_slow_kernel<<<NP / 64, 256, 0, stream>>>(z, e, idx, out, loss);
    }
}